// Round 11
// baseline (62.128 us; speedup 1.0000x reference)
//
#include <hip/hip_runtime.h>

#define DIM 128
#define NGRAPH 4096
#define NSTEM 81920
#define NJROW 81920
#define NOUT 105
#define COLS 2111           // 1 stop + 10 break + 2100 add
#define SPG 20              // stems per graph
#define ROWS 64
#define XPAD 136            // shorts: 272B row stride (conflict-free A-frag b128)
#define TT 4                // tiles per block
#define NBSB 320            // stem blocks  (320*4*64 = 81920 rows)
#define NBJB 320            // jbond blocks

typedef __attribute__((ext_vector_type(8))) short bf16x8;
typedef __attribute__((ext_vector_type(4))) float f32x4;

__device__ __forceinline__ unsigned short f2bf(float f) {
    unsigned int u = __builtin_bit_cast(unsigned int, f);
    return (unsigned short)((u + 0x7fffu + ((u >> 16) & 1u)) >> 16);  // RNE
}
// HW packed f32->bf16 RNE
__device__ __forceinline__ unsigned int cvtpk(float lo, float hi) {
    unsigned int r;
    asm("v_cvt_pk_bf16_f32 %0, %1, %2" : "=v"(r) : "v"(lo), "v"(hi));
    return r;
}
__device__ __forceinline__ float lrelu(float v) { return v > 0.f ? v : 0.01f * v; }

// barrier draining ONLY LDS ops; register-destined gathers stay in flight
__device__ __forceinline__ void lgkm_barrier() {
    asm volatile("s_waitcnt lgkmcnt(0)" ::: "memory");
    __builtin_amdgcn_s_barrier();
}

// ---- prep: pack weights to MFMA frag order + scalar outs (R9's, coalesced)
__global__ __launch_bounds__(256) void prep_kernel(
    const float* __restrict__ W1s, const float* __restrict__ W2s,
    const float* __restrict__ W1j, const float* __restrict__ so,
    short* __restrict__ ws, float* __restrict__ out)
{
    int b = blockIdx.x;
    if (b < 24) {
        int mat = b >> 3, rg = b & 7;
        const float* W; short* dst; int NT, N;
        if (mat == 0)      { W = W1s; dst = ws;         NT = 8; N = 128; }
        else if (mat == 1) { W = W2s; dst = ws + 16384; NT = 7; N = 105; }
        else               { W = W1j; dst = ws + 30720; NT = 8; N = 128; }
        int Npad = NT * 16;
        int r2 = threadIdx.x >> 7;
        int n  = threadIdx.x & 127;
        #pragma unroll
        for (int rr = 0; rr < 16; rr += 2) {
            int k = rg * 16 + rr + r2;
            if (n < Npad) {
                float v = (n < N) ? W[k * N + n] : 0.f;
                int kt = k >> 5, i = k & 7, sub = (k >> 3) & 3;
                int lane = sub * 16 + (n & 15), nt = n >> 4;
                dst[((kt * NT + nt) * 64 + lane) * 8 + i] = (short)f2bf(v);
            }
        }
    } else {
        int g = (b - 24) * 256 + threadIdx.x;
        if (g < NGRAPH) {
            float2 v = *(const float2*)(so + 2 * g);
            out[g] = v.x;
            out[NGRAPH + g * COLS] = v.y;
        }
    }
}

__device__ __forceinline__ void issue_gather(const float* __restrict__ atom,
                                             const int (&a)[4], int ko, float4 (&g)[8])
{
    #pragma unroll
    for (int q = 0; q < 4; ++q) {
        g[2*q]   = *(const float4*)(atom + a[q] * DIM + ko);
        g[2*q+1] = *(const float4*)(atom + a[q] * DIM + ko + 4);
    }
}

__device__ __forceinline__ void stage_lds(short (*X)[XPAD], int rb, int ko,
                                          const float4 (&g)[8])
{
    #pragma unroll
    for (int q = 0; q < 4; ++q) {
        uint4 p;
        p.x = cvtpk(g[2*q].x,   g[2*q].y);
        p.y = cvtpk(g[2*q].z,   g[2*q].w);
        p.z = cvtpk(g[2*q+1].x, g[2*q+1].y);
        p.w = cvtpk(g[2*q+1].z, g[2*q+1].w);
        *(uint4*)&X[q * 16 + rb][ko] = p;
    }
}

// ---- fused stem+jbond. R9 structure + in-place H (LDS 35.8KB) + streamed wf2
// -> 4 blocks/CU target. L1 swapped (mfma(W,X)), L2 unswapped, normal stores.
__global__ __launch_bounds__(256, 4) void fused_mlp(
    const float* __restrict__ atom,
    const int* __restrict__ sidx, const int* __restrict__ jidx,
    const short* __restrict__ wsp,
    const float* __restrict__ b1s, const float* __restrict__ b2s,
    const float* __restrict__ b1j,
    const float* __restrict__ W2j, const float* __restrict__ b2j,
    float* __restrict__ out)
{
    __shared__ short Xbuf[2][ROWS][XPAD];
    __shared__ float red[4][ROWS];
    const int tid = threadIdx.x;
    const bool isStem = blockIdx.x < NBSB;
    const int pb = isStem ? blockIdx.x : blockIdx.x - NBSB;
    const int w = tid >> 6, l = tid & 63;
    const int lq = l >> 4, lc = l & 15;
    const int rb = tid >> 4, ko = (tid & 15) * 8;

    const int*   idx = isStem ? sidx : jidx;
    const short* W1p = isStem ? wsp : wsp + 30720;
    const float* b1  = isStem ? b1s : b1j;
    const int tbase = pb * TT * ROWS;

    // lazy index loads: only tiles 0,1 up front; a[t+2] loaded inside tile t
    int a[TT][4];
    #pragma unroll
    for (int t = 0; t < 2; ++t)
        #pragma unroll
        for (int q = 0; q < 4; ++q)
            a[t][q] = idx[tbase + t * ROWS + q * 16 + rb];

    float4 g[8];
    issue_gather(atom, a[0], ko, g);

    bf16x8 wf1[4][2];
    #pragma unroll
    for (int kt = 0; kt < 4; ++kt)
        #pragma unroll
        for (int j = 0; j < 2; ++j)
            wf1[kt][j] = *(const bf16x8*)(W1p + ((kt * 8 + w * 2 + j) * 64 + l) * 8);

    float4 bb1[2];
    #pragma unroll
    for (int j = 0; j < 2; ++j)
        bb1[j] = *(const float4*)(b1 + (w * 2 + j) * 16 + lq * 4);

    float bb2[2];
    int nt2[2];
    float4 wvj[2];
    float bj = 0.f;
    if (isStem) {
        #pragma unroll
        for (int j = 0; j < 2; ++j) {
            int nt = w * 2 + j;
            nt2[j] = nt > 6 ? 6 : nt;            // clamp; results masked at store
            int c = nt * 16 + lc;
            bb2[j] = (c < NOUT) ? b2s[c] : 0.f;
        }
    } else {
        #pragma unroll
        for (int j = 0; j < 2; ++j)
            wvj[j] = *(const float4*)(W2j + (w * 2 + j) * 16 + lq * 4);
        bj = b2j[0];
    }

    stage_lds(Xbuf[0], rb, ko, g);
    lgkm_barrier();

    if (isStem) {
        const short* W2p = wsp + 16384;
        #pragma unroll
        for (int t = 0; t < TT; ++t) {
            short (*XA)[XPAD] = Xbuf[t & 1];
            short (*XB)[XPAD] = Xbuf[(t + 1) & 1];
            if (t + 1 < TT) issue_gather(atom, a[t + 1], ko, g);
            if (t + 2 < TT)
                #pragma unroll
                for (int q = 0; q < 4; ++q)
                    a[t + 2][q] = idx[tbase + (t + 2) * ROWS + q * 16 + rb];

            // ---- L1 swapped: acc[m][j][rg] = H[s=m*16+lc][c=(w*2+j)*16+lq*4+rg]
            f32x4 acc[4][2];
            #pragma unroll
            for (int j = 0; j < 2; ++j)
                #pragma unroll
                for (int m = 0; m < 4; ++m)
                    acc[m][j] = (f32x4){bb1[j].x, bb1[j].y, bb1[j].z, bb1[j].w};
            #pragma unroll
            for (int kt = 0; kt < 4; ++kt) {
                bf16x8 A0 = *(const bf16x8*)&XA[lc]     [kt * 32 + lq * 8];
                bf16x8 A1 = *(const bf16x8*)&XA[16 + lc][kt * 32 + lq * 8];
                bf16x8 A2 = *(const bf16x8*)&XA[32 + lc][kt * 32 + lq * 8];
                bf16x8 A3 = *(const bf16x8*)&XA[48 + lc][kt * 32 + lq * 8];
                #pragma unroll
                for (int j = 0; j < 2; ++j) {
                    acc[0][j] = __builtin_amdgcn_mfma_f32_16x16x32_bf16(wf1[kt][j], A0, acc[0][j], 0, 0, 0);
                    acc[1][j] = __builtin_amdgcn_mfma_f32_16x16x32_bf16(wf1[kt][j], A1, acc[1][j], 0, 0, 0);
                    acc[2][j] = __builtin_amdgcn_mfma_f32_16x16x32_bf16(wf1[kt][j], A2, acc[2][j], 0, 0, 0);
                    acc[3][j] = __builtin_amdgcn_mfma_f32_16x16x32_bf16(wf1[kt][j], A3, acc[3][j], 0, 0, 0);
                }
            }
            lgkm_barrier();                     // a0: all waves done reading XA as X

            // H -> XA in place (2 cvt_pk + 1 b64 write per (m,j))
            #pragma unroll
            for (int m = 0; m < 4; ++m)
                #pragma unroll
                for (int j = 0; j < 2; ++j) {
                    uint2 hp;
                    hp.x = cvtpk(lrelu(acc[m][j][0]), lrelu(acc[m][j][1]));
                    hp.y = cvtpk(lrelu(acc[m][j][2]), lrelu(acc[m][j][3]));
                    *(uint2*)&XA[m * 16 + lc][(w * 2 + j) * 16 + lq * 4] = hp;
                }
            lgkm_barrier();                     // a1: H visible

            // ---- L2 unswapped; wf2 streamed per-kt (L1-hot after tile 0)
            f32x4 acc2[4][2];
            #pragma unroll
            for (int j = 0; j < 2; ++j)
                #pragma unroll
                for (int m = 0; m < 4; ++m)
                    acc2[m][j] = (f32x4){bb2[j], bb2[j], bb2[j], bb2[j]};
            #pragma unroll
            for (int kt = 0; kt < 4; ++kt) {
                bf16x8 wf2[2];
                #pragma unroll
                for (int j = 0; j < 2; ++j)
                    wf2[j] = *(const bf16x8*)(W2p + ((kt * 7 + nt2[j]) * 64 + l) * 8);
                bf16x8 A0 = *(const bf16x8*)&XA[lc]     [kt * 32 + lq * 8];
                bf16x8 A1 = *(const bf16x8*)&XA[16 + lc][kt * 32 + lq * 8];
                bf16x8 A2 = *(const bf16x8*)&XA[32 + lc][kt * 32 + lq * 8];
                bf16x8 A3 = *(const bf16x8*)&XA[48 + lc][kt * 32 + lq * 8];
                #pragma unroll
                for (int j = 0; j < 2; ++j) {
                    acc2[0][j] = __builtin_amdgcn_mfma_f32_16x16x32_bf16(A0, wf2[j], acc2[0][j], 0, 0, 0);
                    acc2[1][j] = __builtin_amdgcn_mfma_f32_16x16x32_bf16(A1, wf2[j], acc2[1][j], 0, 0, 0);
                    acc2[2][j] = __builtin_amdgcn_mfma_f32_16x16x32_bf16(A2, wf2[j], acc2[2][j], 0, 0, 0);
                    acc2[3][j] = __builtin_amdgcn_mfma_f32_16x16x32_bf16(A3, wf2[j], acc2[3][j], 0, 0, 0);
                }
            }

            const int baseS = tbase + t * ROWS;
            #pragma unroll
            for (int m = 0; m < 4; ++m)
                #pragma unroll
                for (int rg = 0; rg < 4; ++rg) {
                    int S = baseS + m * 16 + lq * 4 + rg;
                    int gph = S / SPG, sl = S - gph * SPG;
                    float* ob = out + NGRAPH + gph * COLS + 1 + 10 + sl * NOUT;
                    #pragma unroll
                    for (int j = 0; j < 2; ++j) {
                        int c = (w * 2 + j) * 16 + lc;
                        if (c < NOUT) ob[c] = acc2[m][j][rg];
                    }
                }

            if (t + 1 < TT) stage_lds(XB, rb, ko, g);
            lgkm_barrier();                     // beta: Xnext visible, XA(L2) reads done
        }
    } else {
        #pragma unroll
        for (int t = 0; t < TT; ++t) {
            short (*XA)[XPAD] = Xbuf[t & 1];
            short (*XB)[XPAD] = Xbuf[(t + 1) & 1];
            if (t + 1 < TT) issue_gather(atom, a[t + 1], ko, g);
            if (t + 2 < TT)
                #pragma unroll
                for (int q = 0; q < 4; ++q)
                    a[t + 2][q] = idx[tbase + (t + 2) * ROWS + q * 16 + rb];

            f32x4 acc[4][2];
            #pragma unroll
            for (int j = 0; j < 2; ++j)
                #pragma unroll
                for (int m = 0; m < 4; ++m)
                    acc[m][j] = (f32x4){bb1[j].x, bb1[j].y, bb1[j].z, bb1[j].w};
            #pragma unroll
            for (int kt = 0; kt < 4; ++kt) {
                bf16x8 A0 = *(const bf16x8*)&XA[lc]     [kt * 32 + lq * 8];
                bf16x8 A1 = *(const bf16x8*)&XA[16 + lc][kt * 32 + lq * 8];
                bf16x8 A2 = *(const bf16x8*)&XA[32 + lc][kt * 32 + lq * 8];
                bf16x8 A3 = *(const bf16x8*)&XA[48 + lc][kt * 32 + lq * 8];
                #pragma unroll
                for (int j = 0; j < 2; ++j) {
                    acc[0][j] = __builtin_amdgcn_mfma_f32_16x16x32_bf16(wf1[kt][j], A0, acc[0][j], 0, 0, 0);
                    acc[1][j] = __builtin_amdgcn_mfma_f32_16x16x32_bf16(wf1[kt][j], A1, acc[1][j], 0, 0, 0);
                    acc[2][j] = __builtin_amdgcn_mfma_f32_16x16x32_bf16(wf1[kt][j], A2, acc[2][j], 0, 0, 0);
                    acc[3][j] = __builtin_amdgcn_mfma_f32_16x16x32_bf16(wf1[kt][j], A3, acc[3][j], 0, 0, 0);
                }
            }

            float pf[4];
            #pragma unroll
            for (int m = 0; m < 4; ++m) {
                float p = 0.f;
                #pragma unroll
                for (int j = 0; j < 2; ++j) {
                    p += lrelu(acc[m][j][0]) * wvj[j].x;
                    p += lrelu(acc[m][j][1]) * wvj[j].y;
                    p += lrelu(acc[m][j][2]) * wvj[j].z;
                    p += lrelu(acc[m][j][3]) * wvj[j].w;
                }
                pf[m] = p;
            }
            #pragma unroll
            for (int m = 0; m < 4; ++m) {
                pf[m] += __shfl_xor(pf[m], 16, 64);
                pf[m] += __shfl_xor(pf[m], 32, 64);
            }
            if (l < 16)
                #pragma unroll
                for (int m = 0; m < 4; ++m)
                    red[w][m * 16 + l] = pf[m];
            lgkm_barrier();                     // alpha: red visible

            if (tid < 32) {
                int r0 = tid * 2;
                float s0 = red[0][r0] + red[1][r0] + red[2][r0] + red[3][r0];
                float s1 = red[0][r0+1] + red[1][r0+1] + red[2][r0+1] + red[3][r0+1];
                float v = (s0 + s1) * 0.5f + bj;
                int B = (pb * TT + t) * 32 + tid;
                int gg = B / 10, c = B - gg * 10;
                out[NGRAPH + gg * COLS + 1 + c] = v;
            }
            if (t + 1 < TT) stage_lds(XB, rb, ko, g);
            lgkm_barrier();                     // beta: Xnext visible, red reads done
        }
    }
}

extern "C" void kernel_launch(void* const* d_in, const int* in_sizes, int n_in,
                              void* d_out, int out_size, void* d_ws, size_t ws_size,
                              hipStream_t stream) {
    const float* per_atom_out = (const float*)d_in[0];
    const float* scalar_outs  = (const float*)d_in[1];
    const int*   stem_atmidx  = (const int*)d_in[2];
    const int*   jbond_atmidx = (const int*)d_in[3];
    const float* W1s = (const float*)d_in[5];
    const float* b1s = (const float*)d_in[6];
    const float* W2s = (const float*)d_in[7];
    const float* b2s = (const float*)d_in[8];
    const float* W1j = (const float*)d_in[9];
    const float* b1j = (const float*)d_in[10];
    const float* W2j = (const float*)d_in[11];
    const float* b2j = (const float*)d_in[12];
    float* out = (float*)d_out;
    short* wsp = (short*)d_ws;   // needs 94208 B

    hipLaunchKernelGGL(prep_kernel, dim3(40), dim3(256), 0, stream,
                       W1s, W2s, W1j, scalar_outs, wsp, out);
    hipLaunchKernelGGL(fused_mlp, dim3(NBSB + NBJB), dim3(256), 0, stream,
                       per_atom_out, stem_atmidx, jbond_atmidx, wsp,
                       b1s, b2s, b1j, W2j, b2j, out);
}

// Round 12
// 42.211 us; speedup vs baseline: 1.4718x; 1.4718x over previous
//
#include <hip/hip_runtime.h>

#define DIM 128
#define NGRAPH 4096
#define NSTEM 81920
#define NJROW 81920
#define NOUT 105
#define COLS 2111           // 1 stop + 10 break + 2100 add
#define SPG 20              // stems per graph
#define ROWS 64
#define XPAD 136            // shorts: 272B row stride
#define TT 4                // tiles per block
#define NBSB 320            // stem blocks  (320*4*64 = 81920 rows)
#define NBJB 320            // jbond blocks

typedef __attribute__((ext_vector_type(8))) short bf16x8;
typedef __attribute__((ext_vector_type(4))) float f32x4;

__device__ __forceinline__ unsigned short f2bf(float f) {
    unsigned int u = __builtin_bit_cast(unsigned int, f);
    return (unsigned short)((u + 0x7fffu + ((u >> 16) & 1u)) >> 16);  // RNE
}
// HW packed f32->bf16 RNE
__device__ __forceinline__ unsigned int cvtpk(float lo, float hi) {
    unsigned int r;
    asm("v_cvt_pk_bf16_f32 %0, %1, %2" : "=v"(r) : "v"(lo), "v"(hi));
    return r;
}
__device__ __forceinline__ float lrelu(float v) { return v > 0.f ? v : 0.01f * v; }

// barrier draining ONLY LDS ops (R8: neutral vs __syncthreads, never worse)
__device__ __forceinline__ void lgkm_barrier() {
    asm volatile("s_waitcnt lgkmcnt(0)" ::: "memory");
    __builtin_amdgcn_s_barrier();
}

// ---- prep: pack weights to MFMA frag order + scalar outs. All 16 loads
// issued independently BEFORE any store (no load->store->load serial chain).
__global__ __launch_bounds__(256) void prep_kernel(
    const float* __restrict__ W1s, const float* __restrict__ W2s,
    const float* __restrict__ W1j, const float* __restrict__ so,
    short* __restrict__ ws, float* __restrict__ out)
{
    int b = blockIdx.x;
    if (b < 24) {
        int mat = b >> 3, rg = b & 7;
        const float* W; short* dst; int NT, N;
        if (mat == 0)      { W = W1s; dst = ws;         NT = 8; N = 128; }
        else if (mat == 1) { W = W2s; dst = ws + 16384; NT = 7; N = 105; }
        else               { W = W1j; dst = ws + 30720; NT = 8; N = 128; }
        int Npad = NT * 16;
        int r2 = threadIdx.x >> 7;       // 0..1
        int n  = threadIdx.x & 127;
        if (n < Npad) {
            float v[8];
            #pragma unroll
            for (int rr = 0; rr < 8; ++rr) {         // batch all loads first
                int k = rg * 16 + rr * 2 + r2;
                v[rr] = (n < N) ? W[k * N + n] : 0.f;
            }
            #pragma unroll
            for (int rr = 0; rr < 8; ++rr) {
                int k = rg * 16 + rr * 2 + r2;
                int kt = k >> 5, i = k & 7, sub = (k >> 3) & 3;
                int lane = sub * 16 + (n & 15), nt = n >> 4;
                dst[((kt * NT + nt) * 64 + lane) * 8 + i] = (short)f2bf(v[rr]);
            }
        }
    } else {
        int g = (b - 24) * 256 + threadIdx.x;
        if (g < NGRAPH) {
            float2 v = *(const float2*)(so + 2 * g);
            out[g] = v.x;
            out[NGRAPH + g * COLS] = v.y;
        }
    }
}

__device__ __forceinline__ void issue_gather(const float* __restrict__ atom,
                                             const int (&a)[4], int ko, float4 (&g)[8])
{
    #pragma unroll
    for (int q = 0; q < 4; ++q) {
        g[2*q]   = *(const float4*)(atom + a[q] * DIM + ko);
        g[2*q+1] = *(const float4*)(atom + a[q] * DIM + ko + 4);
    }
}

__device__ __forceinline__ void stage_lds(short (*X)[XPAD], int rb, int ko,
                                          const float4 (&g)[8])
{
    #pragma unroll
    for (int q = 0; q < 4; ++q) {
        uint4 p;
        p.x = cvtpk(g[2*q].x,   g[2*q].y);
        p.y = cvtpk(g[2*q].z,   g[2*q].w);
        p.z = cvtpk(g[2*q+1].x, g[2*q+1].y);
        p.w = cvtpk(g[2*q+1].z, g[2*q+1].w);
        *(uint4*)&X[q * 16 + rb][ko] = p;
    }
}

// ---- fused stem+jbond MLP (R9 structure exactly), parity-interleaved blocks:
// even bid -> stem, odd bid -> jbond, so each CU gets a balanced mix.
__global__ __launch_bounds__(256, 2) void fused_mlp(
    const float* __restrict__ atom,
    const int* __restrict__ sidx, const int* __restrict__ jidx,
    const short* __restrict__ wsp,
    const float* __restrict__ b1s, const float* __restrict__ b2s,
    const float* __restrict__ b1j,
    const float* __restrict__ W2j, const float* __restrict__ b2j,
    float* __restrict__ out)
{
    __shared__ short Xbuf[2][ROWS][XPAD];
    __shared__ short Hbuf[ROWS][XPAD];
    __shared__ float red[4][ROWS];
    const int tid = threadIdx.x;
    const bool isStem = (blockIdx.x & 1) == 0;    // parity interleave
    const int pb = blockIdx.x >> 1;
    const int w = tid >> 6, l = tid & 63;
    const int lq = l >> 4, lc = l & 15;
    const int rb = tid >> 4, ko = (tid & 15) * 8;

    const int*   idx = isStem ? sidx : jidx;
    const short* W1p = isStem ? wsp : wsp + 30720;
    const float* b1  = isStem ? b1s : b1j;
    const int tbase = pb * TT * ROWS;

    int a[TT][4];
    #pragma unroll
    for (int t = 0; t < TT; ++t)
        #pragma unroll
        for (int q = 0; q < 4; ++q)
            a[t][q] = idx[tbase + t * ROWS + q * 16 + rb];

    float4 g[8];
    issue_gather(atom, a[0], ko, g);

    bf16x8 wf1[4][2];
    #pragma unroll
    for (int kt = 0; kt < 4; ++kt)
        #pragma unroll
        for (int j = 0; j < 2; ++j)
            wf1[kt][j] = *(const bf16x8*)(W1p + ((kt * 8 + w * 2 + j) * 64 + l) * 8);

    // L1 swapped layout: lane's 4 acc entries are channels c0..c0+3
    float4 bb1[2];
    #pragma unroll
    for (int j = 0; j < 2; ++j)
        bb1[j] = *(const float4*)(b1 + (w * 2 + j) * 16 + lq * 4);

    bf16x8 wf2[4][2];
    float bb2[2];
    float4 wvj[2];
    float bj = 0.f;
    if (isStem) {
        const short* W2p = wsp + 16384;
        #pragma unroll
        for (int kt = 0; kt < 4; ++kt)
            #pragma unroll
            for (int j = 0; j < 2; ++j) {
                int nt = w * 2 + j; if (nt > 6) nt = 6;   // clamp; results masked
                wf2[kt][j] = *(const bf16x8*)(W2p + ((kt * 7 + nt) * 64 + l) * 8);
            }
        #pragma unroll
        for (int j = 0; j < 2; ++j) {
            int c = (w * 2 + j) * 16 + lc;                // L2 unswapped: col=lc
            bb2[j] = (c < NOUT) ? b2s[c] : 0.f;
        }
    } else {
        #pragma unroll
        for (int j = 0; j < 2; ++j)
            wvj[j] = *(const float4*)(W2j + (w * 2 + j) * 16 + lq * 4);
        bj = b2j[0];
    }

    stage_lds(Xbuf[0], rb, ko, g);
    lgkm_barrier();

    if (isStem) {
        #pragma unroll
        for (int t = 0; t < TT; ++t) {
            if (t + 1 < TT) issue_gather(atom, a[t + 1], ko, g);

            // ---- L1 swapped: acc[m][j][rg] = H[s=m*16+lc][c=(w*2+j)*16+lq*4+rg]
            f32x4 acc[4][2];
            #pragma unroll
            for (int j = 0; j < 2; ++j)
                #pragma unroll
                for (int m = 0; m < 4; ++m)
                    acc[m][j] = (f32x4){bb1[j].x, bb1[j].y, bb1[j].z, bb1[j].w};
            #pragma unroll
            for (int kt = 0; kt < 4; ++kt) {
                bf16x8 A0 = *(const bf16x8*)&Xbuf[t & 1][lc]     [kt * 32 + lq * 8];
                bf16x8 A1 = *(const bf16x8*)&Xbuf[t & 1][16 + lc][kt * 32 + lq * 8];
                bf16x8 A2 = *(const bf16x8*)&Xbuf[t & 1][32 + lc][kt * 32 + lq * 8];
                bf16x8 A3 = *(const bf16x8*)&Xbuf[t & 1][48 + lc][kt * 32 + lq * 8];
                #pragma unroll
                for (int j = 0; j < 2; ++j) {
                    acc[0][j] = __builtin_amdgcn_mfma_f32_16x16x32_bf16(wf1[kt][j], A0, acc[0][j], 0, 0, 0);
                    acc[1][j] = __builtin_amdgcn_mfma_f32_16x16x32_bf16(wf1[kt][j], A1, acc[1][j], 0, 0, 0);
                    acc[2][j] = __builtin_amdgcn_mfma_f32_16x16x32_bf16(wf1[kt][j], A2, acc[2][j], 0, 0, 0);
                    acc[3][j] = __builtin_amdgcn_mfma_f32_16x16x32_bf16(wf1[kt][j], A3, acc[3][j], 0, 0, 0);
                }
            }

            // H-write: 4 consecutive channels per (m,j) -> 2 cvt_pk + 1 b64 write
            #pragma unroll
            for (int m = 0; m < 4; ++m)
                #pragma unroll
                for (int j = 0; j < 2; ++j) {
                    float r0 = lrelu(acc[m][j][0]), r1 = lrelu(acc[m][j][1]);
                    float r2 = lrelu(acc[m][j][2]), r3 = lrelu(acc[m][j][3]);
                    uint2 hp;
                    hp.x = cvtpk(r0, r1);
                    hp.y = cvtpk(r2, r3);
                    *(uint2*)&Hbuf[m * 16 + lc][(w * 2 + j) * 16 + lq * 4] = hp;
                }
            lgkm_barrier();                         // alpha: H visible

            // ---- L2 unswapped: acc2[m][j][rg] = out[s=m*16+lq*4+rg][c=(w*2+j)*16+lc]
            f32x4 acc2[4][2];
            #pragma unroll
            for (int j = 0; j < 2; ++j)
                #pragma unroll
                for (int m = 0; m < 4; ++m)
                    acc2[m][j] = (f32x4){bb2[j], bb2[j], bb2[j], bb2[j]};
            #pragma unroll
            for (int kt = 0; kt < 4; ++kt) {
                bf16x8 A0 = *(const bf16x8*)&Hbuf[lc]     [kt * 32 + lq * 8];
                bf16x8 A1 = *(const bf16x8*)&Hbuf[16 + lc][kt * 32 + lq * 8];
                bf16x8 A2 = *(const bf16x8*)&Hbuf[32 + lc][kt * 32 + lq * 8];
                bf16x8 A3 = *(const bf16x8*)&Hbuf[48 + lc][kt * 32 + lq * 8];
                #pragma unroll
                for (int j = 0; j < 2; ++j) {
                    acc2[0][j] = __builtin_amdgcn_mfma_f32_16x16x32_bf16(A0, wf2[kt][j], acc2[0][j], 0, 0, 0);
                    acc2[1][j] = __builtin_amdgcn_mfma_f32_16x16x32_bf16(A1, wf2[kt][j], acc2[1][j], 0, 0, 0);
                    acc2[2][j] = __builtin_amdgcn_mfma_f32_16x16x32_bf16(A2, wf2[kt][j], acc2[2][j], 0, 0, 0);
                    acc2[3][j] = __builtin_amdgcn_mfma_f32_16x16x32_bf16(A3, wf2[kt][j], acc2[3][j], 0, 0, 0);
                }
            }

            if (t + 1 < TT) stage_lds(Xbuf[(t + 1) & 1], rb, ko, g);

            const int baseS = tbase + t * ROWS;
            #pragma unroll
            for (int m = 0; m < 4; ++m)
                #pragma unroll
                for (int rg = 0; rg < 4; ++rg) {
                    int S = baseS + m * 16 + lq * 4 + rg;
                    int gph = S / SPG, sl = S - gph * SPG;
                    float* ob = out + NGRAPH + gph * COLS + 1 + 10 + sl * NOUT;
                    #pragma unroll
                    for (int j = 0; j < 2; ++j) {
                        int c = (w * 2 + j) * 16 + lc;
                        if (c < NOUT) ob[c] = acc2[m][j][rg];
                    }
                }
            lgkm_barrier();                         // beta: Xnext visible, H reads done
        }
    } else {
        #pragma unroll
        for (int t = 0; t < TT; ++t) {
            if (t + 1 < TT) issue_gather(atom, a[t + 1], ko, g);

            f32x4 acc[4][2];
            #pragma unroll
            for (int j = 0; j < 2; ++j)
                #pragma unroll
                for (int m = 0; m < 4; ++m)
                    acc[m][j] = (f32x4){bb1[j].x, bb1[j].y, bb1[j].z, bb1[j].w};
            #pragma unroll
            for (int kt = 0; kt < 4; ++kt) {
                bf16x8 A0 = *(const bf16x8*)&Xbuf[t & 1][lc]     [kt * 32 + lq * 8];
                bf16x8 A1 = *(const bf16x8*)&Xbuf[t & 1][16 + lc][kt * 32 + lq * 8];
                bf16x8 A2 = *(const bf16x8*)&Xbuf[t & 1][32 + lc][kt * 32 + lq * 8];
                bf16x8 A3 = *(const bf16x8*)&Xbuf[t & 1][48 + lc][kt * 32 + lq * 8];
                #pragma unroll
                for (int j = 0; j < 2; ++j) {
                    acc[0][j] = __builtin_amdgcn_mfma_f32_16x16x32_bf16(wf1[kt][j], A0, acc[0][j], 0, 0, 0);
                    acc[1][j] = __builtin_amdgcn_mfma_f32_16x16x32_bf16(wf1[kt][j], A1, acc[1][j], 0, 0, 0);
                    acc[2][j] = __builtin_amdgcn_mfma_f32_16x16x32_bf16(wf1[kt][j], A2, acc[2][j], 0, 0, 0);
                    acc[3][j] = __builtin_amdgcn_mfma_f32_16x16x32_bf16(wf1[kt][j], A3, acc[3][j], 0, 0, 0);
                }
            }

            // lane holds H[s=m*16+lc][4 channels]: dot with wvj, reduce over lq (16,32)
            float pf[4];
            #pragma unroll
            for (int m = 0; m < 4; ++m) {
                float p = 0.f;
                #pragma unroll
                for (int j = 0; j < 2; ++j) {
                    p += lrelu(acc[m][j][0]) * wvj[j].x;
                    p += lrelu(acc[m][j][1]) * wvj[j].y;
                    p += lrelu(acc[m][j][2]) * wvj[j].z;
                    p += lrelu(acc[m][j][3]) * wvj[j].w;
                }
                pf[m] = p;
            }
            #pragma unroll
            for (int m = 0; m < 4; ++m) {
                pf[m] += __shfl_xor(pf[m], 16, 64);
                pf[m] += __shfl_xor(pf[m], 32, 64);
            }
            if (l < 16)
                #pragma unroll
                for (int m = 0; m < 4; ++m)
                    red[w][m * 16 + l] = pf[m];
            lgkm_barrier();                         // alpha: red visible

            if (tid < 32) {
                int r0 = tid * 2;
                float s0 = red[0][r0] + red[1][r0] + red[2][r0] + red[3][r0];
                float s1 = red[0][r0+1] + red[1][r0+1] + red[2][r0+1] + red[3][r0+1];
                float v = (s0 + s1) * 0.5f + bj;
                int B = (pb * TT + t) * 32 + tid;
                int gg = B / 10, c = B - gg * 10;
                out[NGRAPH + gg * COLS + 1 + c] = v;
            }
            if (t + 1 < TT) stage_lds(Xbuf[(t + 1) & 1], rb, ko, g);
            lgkm_barrier();                         // beta: Xnext visible, red reads done
        }
    }
}

extern "C" void kernel_launch(void* const* d_in, const int* in_sizes, int n_in,
                              void* d_out, int out_size, void* d_ws, size_t ws_size,
                              hipStream_t stream) {
    const float* per_atom_out = (const float*)d_in[0];
    const float* scalar_outs  = (const float*)d_in[1];
    const int*   stem_atmidx  = (const int*)d_in[2];
    const int*   jbond_atmidx = (const int*)d_in[3];
    const float* W1s = (const float*)d_in[5];
    const float* b1s = (const float*)d_in[6];
    const float* W2s = (const float*)d_in[7];
    const float* b2s = (const float*)d_in[8];
    const float* W1j = (const float*)d_in[9];
    const float* b1j = (const float*)d_in[10];
    const float* W2j = (const float*)d_in[11];
    const float* b2j = (const float*)d_in[12];
    float* out = (float*)d_out;
    short* wsp = (short*)d_ws;   // needs 94208 B

    hipLaunchKernelGGL(prep_kernel, dim3(40), dim3(256), 0, stream,
                       W1s, W2s, W1j, scalar_outs, wsp, out);
    hipLaunchKernelGGL(fused_mlp, dim3(NBSB + NBJB), dim3(256), 0, stream,
                       per_atom_out, stem_atmidx, jbond_atmidx, wsp,
                       b1s, b2s, b1j, W2j, b2j, out);
}

// Round 13
// 32.931 us; speedup vs baseline: 1.8866x; 1.2818x over previous
//
#include <hip/hip_runtime.h>

#define DIM 128
#define NGRAPH 4096
#define NSTEM 81920
#define NJROW 81920
#define NOUT 105
#define COLS 2111           // 1 stop + 10 break + 2100 add
#define SPG 20              // stems per graph
#define ROWS 64
#define XPAD 136            // shorts: 272B row stride
#define TT 4                // tiles per block
#define NBSB 320            // stem blocks  (320*4*64 = 81920 rows)
#define NBJB 320            // jbond blocks

typedef __attribute__((ext_vector_type(8))) short bf16x8;
typedef __attribute__((ext_vector_type(4))) float f32x4;

__device__ __forceinline__ unsigned short f2bf(float f) {
    unsigned int u = __builtin_bit_cast(unsigned int, f);
    return (unsigned short)((u + 0x7fffu + ((u >> 16) & 1u)) >> 16);  // RNE
}
// HW packed f32->bf16 RNE
__device__ __forceinline__ unsigned int cvtpk(float lo, float hi) {
    unsigned int r;
    asm("v_cvt_pk_bf16_f32 %0, %1, %2" : "=v"(r) : "v"(lo), "v"(hi));
    return r;
}
__device__ __forceinline__ float lrelu(float v) { return v > 0.f ? v : 0.01f * v; }

// barrier draining ONLY LDS ops (R8: neutral vs __syncthreads, never worse)
__device__ __forceinline__ void lgkm_barrier() {
    asm volatile("s_waitcnt lgkmcnt(0)" ::: "memory");
    __builtin_amdgcn_s_barrier();
}

// ---- prep: pack weights to MFMA frag order + scalar outs. All 8 loads per
// thread issued independently BEFORE any store (no load->store serial chain).
__global__ __launch_bounds__(256) void prep_kernel(
    const float* __restrict__ W1s, const float* __restrict__ W2s,
    const float* __restrict__ W1j, const float* __restrict__ so,
    short* __restrict__ ws, float* __restrict__ out)
{
    int b = blockIdx.x;
    if (b < 24) {
        int mat = b >> 3, rg = b & 7;
        const float* W; short* dst; int NT, N;
        if (mat == 0)      { W = W1s; dst = ws;         NT = 8; N = 128; }
        else if (mat == 1) { W = W2s; dst = ws + 16384; NT = 7; N = 105; }
        else               { W = W1j; dst = ws + 30720; NT = 8; N = 128; }
        int Npad = NT * 16;
        int r2 = threadIdx.x >> 7;       // 0..1
        int n  = threadIdx.x & 127;
        if (n < Npad) {
            float v[8];
            #pragma unroll
            for (int rr = 0; rr < 8; ++rr) {         // batch all loads first
                int k = rg * 16 + rr * 2 + r2;
                v[rr] = (n < N) ? W[k * N + n] : 0.f;
            }
            #pragma unroll
            for (int rr = 0; rr < 8; ++rr) {
                int k = rg * 16 + rr * 2 + r2;
                int kt = k >> 5, i = k & 7, sub = (k >> 3) & 3;
                int lane = sub * 16 + (n & 15), nt = n >> 4;
                dst[((kt * NT + nt) * 64 + lane) * 8 + i] = (short)f2bf(v[rr]);
            }
        }
    } else {
        int g = (b - 24) * 256 + threadIdx.x;
        if (g < NGRAPH) {
            float2 v = *(const float2*)(so + 2 * g);
            out[g] = v.x;
            out[NGRAPH + g * COLS] = v.y;
        }
    }
}

__device__ __forceinline__ void issue_gather(const float* __restrict__ atom,
                                             const int (&a)[4], int ko, float4 (&g)[8])
{
    #pragma unroll
    for (int q = 0; q < 4; ++q) {
        g[2*q]   = *(const float4*)(atom + a[q] * DIM + ko);
        g[2*q+1] = *(const float4*)(atom + a[q] * DIM + ko + 4);
    }
}

__device__ __forceinline__ void stage_lds(short (*X)[XPAD], int rb, int ko,
                                          const float4 (&g)[8])
{
    #pragma unroll
    for (int q = 0; q < 4; ++q) {
        uint4 p;
        p.x = cvtpk(g[2*q].x,   g[2*q].y);
        p.y = cvtpk(g[2*q].z,   g[2*q].w);
        p.z = cvtpk(g[2*q+1].x, g[2*q+1].y);
        p.w = cvtpk(g[2*q+1].z, g[2*q+1].w);
        *(uint4*)&X[q * 16 + rb][ko] = p;
    }
}

// ---- fused stem+jbond MLP: R9 champion structure verbatim.
// CLUSTERED blocks (stem first, jbond second): in-order dispatch backfills
// short jbond blocks behind long stem blocks; interleave regressed 9us (R12).
__global__ __launch_bounds__(256, 2) void fused_mlp(
    const float* __restrict__ atom,
    const int* __restrict__ sidx, const int* __restrict__ jidx,
    const short* __restrict__ wsp,
    const float* __restrict__ b1s, const float* __restrict__ b2s,
    const float* __restrict__ b1j,
    const float* __restrict__ W2j, const float* __restrict__ b2j,
    float* __restrict__ out)
{
    __shared__ short Xbuf[2][ROWS][XPAD];
    __shared__ short Hbuf[ROWS][XPAD];
    __shared__ float red[4][ROWS];
    const int tid = threadIdx.x;
    const bool isStem = blockIdx.x < NBSB;
    const int pb = isStem ? blockIdx.x : blockIdx.x - NBSB;
    const int w = tid >> 6, l = tid & 63;
    const int lq = l >> 4, lc = l & 15;
    const int rb = tid >> 4, ko = (tid & 15) * 8;

    const int*   idx = isStem ? sidx : jidx;
    const short* W1p = isStem ? wsp : wsp + 30720;
    const float* b1  = isStem ? b1s : b1j;
    const int tbase = pb * TT * ROWS;

    int a[TT][4];
    #pragma unroll
    for (int t = 0; t < TT; ++t)
        #pragma unroll
        for (int q = 0; q < 4; ++q)
            a[t][q] = idx[tbase + t * ROWS + q * 16 + rb];

    float4 g[8];
    issue_gather(atom, a[0], ko, g);

    bf16x8 wf1[4][2];
    #pragma unroll
    for (int kt = 0; kt < 4; ++kt)
        #pragma unroll
        for (int j = 0; j < 2; ++j)
            wf1[kt][j] = *(const bf16x8*)(W1p + ((kt * 8 + w * 2 + j) * 64 + l) * 8);

    // L1 swapped layout: lane's 4 acc entries are channels c0..c0+3
    float4 bb1[2];
    #pragma unroll
    for (int j = 0; j < 2; ++j)
        bb1[j] = *(const float4*)(b1 + (w * 2 + j) * 16 + lq * 4);

    bf16x8 wf2[4][2];
    float bb2[2];
    float4 wvj[2];
    float bj = 0.f;
    if (isStem) {
        const short* W2p = wsp + 16384;
        #pragma unroll
        for (int kt = 0; kt < 4; ++kt)
            #pragma unroll
            for (int j = 0; j < 2; ++j) {
                int nt = w * 2 + j; if (nt > 6) nt = 6;   // clamp; results masked
                wf2[kt][j] = *(const bf16x8*)(W2p + ((kt * 7 + nt) * 64 + l) * 8);
            }
        #pragma unroll
        for (int j = 0; j < 2; ++j) {
            int c = (w * 2 + j) * 16 + lc;                // L2 unswapped: col=lc
            bb2[j] = (c < NOUT) ? b2s[c] : 0.f;
        }
    } else {
        #pragma unroll
        for (int j = 0; j < 2; ++j)
            wvj[j] = *(const float4*)(W2j + (w * 2 + j) * 16 + lq * 4);
        bj = b2j[0];
    }

    stage_lds(Xbuf[0], rb, ko, g);
    lgkm_barrier();

    if (isStem) {
        #pragma unroll
        for (int t = 0; t < TT; ++t) {
            if (t + 1 < TT) issue_gather(atom, a[t + 1], ko, g);

            // ---- L1 swapped: acc[m][j][rg] = H[s=m*16+lc][c=(w*2+j)*16+lq*4+rg]
            f32x4 acc[4][2];
            #pragma unroll
            for (int j = 0; j < 2; ++j)
                #pragma unroll
                for (int m = 0; m < 4; ++m)
                    acc[m][j] = (f32x4){bb1[j].x, bb1[j].y, bb1[j].z, bb1[j].w};
            #pragma unroll
            for (int kt = 0; kt < 4; ++kt) {
                bf16x8 A0 = *(const bf16x8*)&Xbuf[t & 1][lc]     [kt * 32 + lq * 8];
                bf16x8 A1 = *(const bf16x8*)&Xbuf[t & 1][16 + lc][kt * 32 + lq * 8];
                bf16x8 A2 = *(const bf16x8*)&Xbuf[t & 1][32 + lc][kt * 32 + lq * 8];
                bf16x8 A3 = *(const bf16x8*)&Xbuf[t & 1][48 + lc][kt * 32 + lq * 8];
                #pragma unroll
                for (int j = 0; j < 2; ++j) {
                    acc[0][j] = __builtin_amdgcn_mfma_f32_16x16x32_bf16(wf1[kt][j], A0, acc[0][j], 0, 0, 0);
                    acc[1][j] = __builtin_amdgcn_mfma_f32_16x16x32_bf16(wf1[kt][j], A1, acc[1][j], 0, 0, 0);
                    acc[2][j] = __builtin_amdgcn_mfma_f32_16x16x32_bf16(wf1[kt][j], A2, acc[2][j], 0, 0, 0);
                    acc[3][j] = __builtin_amdgcn_mfma_f32_16x16x32_bf16(wf1[kt][j], A3, acc[3][j], 0, 0, 0);
                }
            }

            // H-write: 4 consecutive channels per (m,j) -> 2 cvt_pk + 1 b64 write
            #pragma unroll
            for (int m = 0; m < 4; ++m)
                #pragma unroll
                for (int j = 0; j < 2; ++j) {
                    float r0 = lrelu(acc[m][j][0]), r1 = lrelu(acc[m][j][1]);
                    float r2 = lrelu(acc[m][j][2]), r3 = lrelu(acc[m][j][3]);
                    uint2 hp;
                    hp.x = cvtpk(r0, r1);
                    hp.y = cvtpk(r2, r3);
                    *(uint2*)&Hbuf[m * 16 + lc][(w * 2 + j) * 16 + lq * 4] = hp;
                }
            lgkm_barrier();                         // alpha: H visible

            // ---- L2 unswapped: acc2[m][j][rg] = out[s=m*16+lq*4+rg][c=(w*2+j)*16+lc]
            f32x4 acc2[4][2];
            #pragma unroll
            for (int j = 0; j < 2; ++j)
                #pragma unroll
                for (int m = 0; m < 4; ++m)
                    acc2[m][j] = (f32x4){bb2[j], bb2[j], bb2[j], bb2[j]};
            #pragma unroll
            for (int kt = 0; kt < 4; ++kt) {
                bf16x8 A0 = *(const bf16x8*)&Hbuf[lc]     [kt * 32 + lq * 8];
                bf16x8 A1 = *(const bf16x8*)&Hbuf[16 + lc][kt * 32 + lq * 8];
                bf16x8 A2 = *(const bf16x8*)&Hbuf[32 + lc][kt * 32 + lq * 8];
                bf16x8 A3 = *(const bf16x8*)&Hbuf[48 + lc][kt * 32 + lq * 8];
                #pragma unroll
                for (int j = 0; j < 2; ++j) {
                    acc2[0][j] = __builtin_amdgcn_mfma_f32_16x16x32_bf16(A0, wf2[kt][j], acc2[0][j], 0, 0, 0);
                    acc2[1][j] = __builtin_amdgcn_mfma_f32_16x16x32_bf16(A1, wf2[kt][j], acc2[1][j], 0, 0, 0);
                    acc2[2][j] = __builtin_amdgcn_mfma_f32_16x16x32_bf16(A2, wf2[kt][j], acc2[2][j], 0, 0, 0);
                    acc2[3][j] = __builtin_amdgcn_mfma_f32_16x16x32_bf16(A3, wf2[kt][j], acc2[3][j], 0, 0, 0);
                }
            }

            if (t + 1 < TT) stage_lds(Xbuf[(t + 1) & 1], rb, ko, g);

            const int baseS = tbase + t * ROWS;
            #pragma unroll
            for (int m = 0; m < 4; ++m)
                #pragma unroll
                for (int rg = 0; rg < 4; ++rg) {
                    int S = baseS + m * 16 + lq * 4 + rg;
                    int gph = S / SPG, sl = S - gph * SPG;
                    float* ob = out + NGRAPH + gph * COLS + 1 + 10 + sl * NOUT;
                    #pragma unroll
                    for (int j = 0; j < 2; ++j) {
                        int c = (w * 2 + j) * 16 + lc;
                        if (c < NOUT) ob[c] = acc2[m][j][rg];
                    }
                }
            lgkm_barrier();                         // beta: Xnext visible, H reads done
        }
    } else {
        #pragma unroll
        for (int t = 0; t < TT; ++t) {
            if (t + 1 < TT) issue_gather(atom, a[t + 1], ko, g);

            f32x4 acc[4][2];
            #pragma unroll
            for (int j = 0; j < 2; ++j)
                #pragma unroll
                for (int m = 0; m < 4; ++m)
                    acc[m][j] = (f32x4){bb1[j].x, bb1[j].y, bb1[j].z, bb1[j].w};
            #pragma unroll
            for (int kt = 0; kt < 4; ++kt) {
                bf16x8 A0 = *(const bf16x8*)&Xbuf[t & 1][lc]     [kt * 32 + lq * 8];
                bf16x8 A1 = *(const bf16x8*)&Xbuf[t & 1][16 + lc][kt * 32 + lq * 8];
                bf16x8 A2 = *(const bf16x8*)&Xbuf[t & 1][32 + lc][kt * 32 + lq * 8];
                bf16x8 A3 = *(const bf16x8*)&Xbuf[t & 1][48 + lc][kt * 32 + lq * 8];
                #pragma unroll
                for (int j = 0; j < 2; ++j) {
                    acc[0][j] = __builtin_amdgcn_mfma_f32_16x16x32_bf16(wf1[kt][j], A0, acc[0][j], 0, 0, 0);
                    acc[1][j] = __builtin_amdgcn_mfma_f32_16x16x32_bf16(wf1[kt][j], A1, acc[1][j], 0, 0, 0);
                    acc[2][j] = __builtin_amdgcn_mfma_f32_16x16x32_bf16(wf1[kt][j], A2, acc[2][j], 0, 0, 0);
                    acc[3][j] = __builtin_amdgcn_mfma_f32_16x16x32_bf16(wf1[kt][j], A3, acc[3][j], 0, 0, 0);
                }
            }

            // lane holds H[s=m*16+lc][4 channels]: dot with wvj, reduce over lq (16,32)
            float pf[4];
            #pragma unroll
            for (int m = 0; m < 4; ++m) {
                float p = 0.f;
                #pragma unroll
                for (int j = 0; j < 2; ++j) {
                    p += lrelu(acc[m][j][0]) * wvj[j].x;
                    p += lrelu(acc[m][j][1]) * wvj[j].y;
                    p += lrelu(acc[m][j][2]) * wvj[j].z;
                    p += lrelu(acc[m][j][3]) * wvj[j].w;
                }
                pf[m] = p;
            }
            #pragma unroll
            for (int m = 0; m < 4; ++m) {
                pf[m] += __shfl_xor(pf[m], 16, 64);
                pf[m] += __shfl_xor(pf[m], 32, 64);
            }
            if (l < 16)
                #pragma unroll
                for (int m = 0; m < 4; ++m)
                    red[w][m * 16 + l] = pf[m];
            lgkm_barrier();                         // alpha: red visible

            if (tid < 32) {
                int r0 = tid * 2;
                float s0 = red[0][r0] + red[1][r0] + red[2][r0] + red[3][r0];
                float s1 = red[0][r0+1] + red[1][r0+1] + red[2][r0+1] + red[3][r0+1];
                float v = (s0 + s1) * 0.5f + bj;
                int B = (pb * TT + t) * 32 + tid;
                int gg = B / 10, c = B - gg * 10;
                out[NGRAPH + gg * COLS + 1 + c] = v;
            }
            if (t + 1 < TT) stage_lds(Xbuf[(t + 1) & 1], rb, ko, g);
            lgkm_barrier();                         // beta: Xnext visible, red reads done
        }
    }
}

extern "C" void kernel_launch(void* const* d_in, const int* in_sizes, int n_in,
                              void* d_out, int out_size, void* d_ws, size_t ws_size,
                              hipStream_t stream) {
    const float* per_atom_out = (const float*)d_in[0];
    const float* scalar_outs  = (const float*)d_in[1];
    const int*   stem_atmidx  = (const int*)d_in[2];
    const int*   jbond_atmidx = (const int*)d_in[3];
    const float* W1s = (const float*)d_in[5];
    const float* b1s = (const float*)d_in[6];
    const float* W2s = (const float*)d_in[7];
    const float* b2s = (const float*)d_in[8];
    const float* W1j = (const float*)d_in[9];
    const float* b1j = (const float*)d_in[10];
    const float* W2j = (const float*)d_in[11];
    const float* b2j = (const float*)d_in[12];
    float* out = (float*)d_out;
    short* wsp = (short*)d_ws;   // needs 94208 B

    hipLaunchKernelGGL(prep_kernel, dim3(40), dim3(256), 0, stream,
                       W1s, W2s, W1j, scalar_outs, wsp, out);
    hipLaunchKernelGGL(fused_mlp, dim3(NBSB + NBJB), dim3(256), 0, stream,
                       per_atom_out, stem_atmidx, jbond_atmidx, wsp,
                       b1s, b2s, b1j, W2j, b2j, out);
}